// Round 1
// baseline (466.861 us; speedup 1.0000x reference)
//
#include <hip/hip_runtime.h>

#define NQ 10
#define REGS 16  // amplitudes per lane: bits 0..3 of index; lane = bits 4..9

struct cplx { float x, y; };

__device__ __forceinline__ cplx mk(float x, float y){ cplx c; c.x=x; c.y=y; return c; }
__device__ __forceinline__ cplx cmul(cplx a, cplx b){ return mk(a.x*b.x - a.y*b.y, a.x*b.y + a.y*b.x); }
__device__ __forceinline__ cplx cadd(cplx a, cplx b){ return mk(a.x+b.x, a.y+b.y); }
__device__ __forceinline__ cplx shflx(cplx a, int mask){
    cplx r; r.x = __shfl_xor(a.x, mask, 64); r.y = __shfl_xor(a.y, mask, 64); return r;
}

// General single-qubit gate on wire w. new0 = u00*a0 + u01*a1 ; new1 = u10*a0 + u11*a1
__device__ __forceinline__ void apply1q(cplx amp[REGS], int lane, int w,
                                        cplx u00, cplx u01, cplx u10, cplx u11){
    if (w < 4) {
        const int m = 1 << w;
        #pragma unroll
        for (int r = 0; r < REGS; ++r) {
            if (!(r & m)) {
                const int r1 = r | m;
                cplx a0 = amp[r], a1 = amp[r1];
                amp[r]  = cadd(cmul(u00, a0), cmul(u01, a1));
                amp[r1] = cadd(cmul(u10, a0), cmul(u11, a1));
            }
        }
    } else {
        const int lm = 1 << (w - 4);
        const bool hi = (lane & lm) != 0;
        #pragma unroll
        for (int r = 0; r < REGS; ++r) {
            cplx p = shflx(amp[r], lm);
            cplx a0 = hi ? p : amp[r];
            cplx a1 = hi ? amp[r] : p;
            cplx n0 = cadd(cmul(u00, a0), cmul(u01, a1));
            cplx n1 = cadd(cmul(u10, a0), cmul(u11, a1));
            amp[r] = hi ? n1 : n0;
        }
    }
}

// CRX pair update: new0 = cc*a0 - i*ss*a1 ; new1 = -i*ss*a0 + cc*a1
__device__ __forceinline__ void crx_new(cplx a0, cplx a1, float cc, float ss, cplx &n0, cplx &n1){
    n0 = mk(cc*a0.x + ss*a1.y, cc*a0.y - ss*a1.x);
    n1 = mk(ss*a0.y + cc*a1.x, -ss*a0.x + cc*a1.y);
}

__device__ __forceinline__ void apply_crx(cplx amp[REGS], int lane, int c, int t, float cc, float ss){
    if (c < 4 && t < 4) {
        const int mc = 1 << c, mt = 1 << t;
        #pragma unroll
        for (int r = 0; r < REGS; ++r) {
            if ((r & mc) && !(r & mt)) {
                cplx n0, n1;
                crx_new(amp[r], amp[r | mt], cc, ss, n0, n1);
                amp[r] = n0; amp[r | mt] = n1;
            }
        }
    } else if (c < 4) {              // control in regs, target across lanes
        const int mc = 1 << c, lm = 1 << (t - 4);
        const bool hi = (lane & lm) != 0;
        #pragma unroll
        for (int r = 0; r < REGS; ++r) {
            if (r & mc) {            // r is a compile-time constant after unroll: wave-uniform
                cplx p = shflx(amp[r], lm);
                cplx a0 = hi ? p : amp[r];
                cplx a1 = hi ? amp[r] : p;
                cplx n0, n1;
                crx_new(a0, a1, cc, ss, n0, n1);
                amp[r] = hi ? n1 : n0;
            }
        }
    } else if (t < 4) {              // control in lane bits, target in regs
        const int clm = 1 << (c - 4), mt = 1 << t;
        if (lane & clm) {
            #pragma unroll
            for (int r = 0; r < REGS; ++r) {
                if (!(r & mt)) {
                    cplx n0, n1;
                    crx_new(amp[r], amp[r | mt], cc, ss, n0, n1);
                    amp[r] = n0; amp[r | mt] = n1;
                }
            }
        }
    } else {                         // both in lane bits
        const int clm = 1 << (c - 4), tlm = 1 << (t - 4);
        const bool ctl = (lane & clm) != 0;
        const bool hi  = (lane & tlm) != 0;
        #pragma unroll
        for (int r = 0; r < REGS; ++r) {
            cplx p = shflx(amp[r], tlm);   // executed by all lanes (shuffle safety)
            if (ctl) {
                cplx a0 = hi ? p : amp[r];
                cplx a1 = hi ? amp[r] : p;
                cplx n0, n1;
                crx_new(a0, a1, cc, ss, n0, n1);
                amp[r] = hi ? n1 : n0;
            }
        }
    }
}

__device__ __forceinline__ void apply_cnot(cplx amp[REGS], int lane, int c, int t){
    if (c < 4 && t < 4) {
        const int mc = 1 << c, mt = 1 << t;
        #pragma unroll
        for (int r = 0; r < REGS; ++r) {
            if ((r & mc) && !(r & mt)) {
                cplx tmp = amp[r]; amp[r] = amp[r | mt]; amp[r | mt] = tmp;
            }
        }
    } else if (c < 4) {              // control in regs, target across lanes: swap == take partner
        const int mc = 1 << c, lm = 1 << (t - 4);
        #pragma unroll
        for (int r = 0; r < REGS; ++r)
            if (r & mc)
                amp[r] = shflx(amp[r], lm);
    } else if (t < 4) {              // control in lane bits, target in regs
        const int clm = 1 << (c - 4), mt = 1 << t;
        if (lane & clm) {
            #pragma unroll
            for (int r = 0; r < REGS; ++r) {
                if (!(r & mt)) {
                    cplx tmp = amp[r]; amp[r] = amp[r | mt]; amp[r | mt] = tmp;
                }
            }
        }
    } else {                         // both in lane bits
        const int clm = 1 << (c - 4), tlm = 1 << (t - 4);
        const bool ctl = (lane & clm) != 0;
        #pragma unroll
        for (int r = 0; r < REGS; ++r) {
            cplx p = shflx(amp[r], tlm);
            if (ctl) amp[r] = p;
        }
    }
}

__global__ __launch_bounds__(256) void qsim_kernel(const float* __restrict__ inputs,
                                                   const float* __restrict__ weights,
                                                   float* __restrict__ out, int B){
    const int wave = (int)((blockIdx.x * blockDim.x + threadIdx.x) >> 6);
    const int lane = threadIdx.x & 63;
    if (wave >= B) return;

    const float* ang = inputs + (size_t)wave * NQ;

    cplx amp[REGS];
    #pragma unroll
    for (int r = 0; r < REGS; ++r) amp[r] = mk(0.f, 0.f);
    amp[0].x = (lane == 0) ? 1.f : 0.f;

    // ---- AngleEmbedding: RY(inputs[b, w]) on wire w ----
    #pragma unroll
    for (int w = 0; w < NQ; ++w) {
        float th = 0.5f * ang[w];
        float c = cosf(th), s = sinf(th);
        apply1q(amp, lane, w, mk(c, 0.f), mk(-s, 0.f), mk(s, 0.f), mk(c, 0.f));
    }

    // ---- CRX(pi/3) over chain edges ----
    const float cc = 0.86602540378443864676f;  // cos(pi/6)
    const float ss = 0.5f;                     // sin(pi/6)
    apply_crx(amp, lane, 0, 1, cc, ss);
    apply_crx(amp, lane, 1, 2, cc, ss);
    apply_crx(amp, lane, 2, 3, cc, ss);
    apply_crx(amp, lane, 3, 4, cc, ss);
    apply_crx(amp, lane, 4, 5, cc, ss);
    apply_crx(amp, lane, 5, 6, cc, ss);
    apply_crx(amp, lane, 6, 7, cc, ss);
    apply_crx(amp, lane, 7, 8, cc, ss);
    apply_crx(amp, lane, 8, 9, cc, ss);
    apply_crx(amp, lane, 9, 0, cc, ss);

    // ---- StronglyEntanglingLayers: Rot per wire then CNOT(i, (i+2)%10) ----
    #pragma unroll
    for (int i = 0; i < NQ; ++i) {
        float phi = weights[i*3 + 0], th = weights[i*3 + 1], om = weights[i*3 + 2];
        float ct = cosf(0.5f * th), st = sinf(0.5f * th);
        float ap = 0.5f * (phi + om), am = 0.5f * (phi - om);
        float ca = cosf(ap), sa = sinf(ap);
        float cb = cosf(am), sb = sinf(am);
        cplx u00 = mk( ct * ca, -ct * sa);
        cplx u01 = mk(-st * cb, -st * sb);
        cplx u10 = mk( st * cb, -st * sb);
        cplx u11 = mk( ct * ca,  ct * sa);
        apply1q(amp, lane, i, u00, u01, u10, u11);
    }
    apply_cnot(amp, lane, 0, 2);
    apply_cnot(amp, lane, 1, 3);
    apply_cnot(amp, lane, 2, 4);
    apply_cnot(amp, lane, 3, 5);
    apply_cnot(amp, lane, 4, 6);
    apply_cnot(amp, lane, 5, 7);
    apply_cnot(amp, lane, 6, 8);
    apply_cnot(amp, lane, 7, 9);
    apply_cnot(amp, lane, 8, 0);
    apply_cnot(amp, lane, 9, 1);

    // ---- expval(PauliZ(w)) ----
    float p[REGS];
    float tot = 0.f;
    #pragma unroll
    for (int r = 0; r < REGS; ++r) {
        p[r] = amp[r].x * amp[r].x + amp[r].y * amp[r].y;
        tot += p[r];
    }
    float ex[NQ];
    #pragma unroll
    for (int w = 0; w < 4; ++w) {
        float s = 0.f;
        #pragma unroll
        for (int r = 0; r < REGS; ++r)
            s += ((r >> w) & 1) ? -p[r] : p[r];
        ex[w] = s;
    }
    #pragma unroll
    for (int w = 4; w < NQ; ++w)
        ex[w] = ((lane >> (w - 4)) & 1) ? -tot : tot;

    #pragma unroll
    for (int w = 0; w < NQ; ++w) {
        float v = ex[w];
        #pragma unroll
        for (int off = 32; off > 0; off >>= 1)
            v += __shfl_xor(v, off, 64);
        ex[w] = v;
    }
    if (lane == 0) {
        #pragma unroll
        for (int w = 0; w < NQ; ++w)
            out[(size_t)wave * NQ + w] = ex[w];
    }
}

extern "C" void kernel_launch(void* const* d_in, const int* in_sizes, int n_in,
                              void* d_out, int out_size, void* d_ws, size_t ws_size,
                              hipStream_t stream) {
    const float* inputs  = (const float*)d_in[0];   // (B, 10) float32
    const float* weights = (const float*)d_in[1];   // (1, 10, 3) float32
    float* out = (float*)d_out;                     // (B, 10) float32
    const int B = in_sizes[0] / NQ;
    const int wavesPerBlock = 256 / 64;
    const int blocks = (B + wavesPerBlock - 1) / wavesPerBlock;
    qsim_kernel<<<blocks, 256, 0, stream>>>(inputs, weights, out, B);
}

// Round 2
// 125.963 us; speedup vs baseline: 3.7063x; 3.7063x over previous
//
#include <hip/hip_runtime.h>

#define NQ 10

struct cplx { float x, y; };

__device__ __forceinline__ cplx mk(float x, float y){ cplx c; c.x=x; c.y=y; return c; }
__device__ __forceinline__ cplx cmul(cplx a, cplx b){ return mk(a.x*b.x - a.y*b.y, a.x*b.y + a.y*b.x); }
__device__ __forceinline__ cplx cadd(cplx a, cplx b){ return mk(a.x+b.x, a.y+b.y); }
__device__ __forceinline__ cplx shflx(cplx a, int m){
    cplx r; r.x = __shfl_xor(a.x, m, 64); r.y = __shfl_xor(a.y, m, 64); return r;
}

// ===== 1-qubit gate helpers (all amp indices are template constants => SROA-safe) =====

// wire in reg bits: pair (R, R|M)
template<int M, int R>
__device__ __forceinline__ void g1_reg(cplx (&a)[16], cplx u00, cplx u01, cplx u10, cplx u11){
    if constexpr (R < 16) {
        if constexpr ((R & M) == 0) {
            cplx a0 = a[R], a1 = a[R|M];
            a[R]   = cadd(cmul(u00,a0), cmul(u01,a1));
            a[R|M] = cadd(cmul(u10,a0), cmul(u11,a1));
        }
        g1_reg<M, R+1>(a, u00,u01,u10,u11);
    }
}

// wire in lane bits: exchange with lane^LM
template<int LM, int R>
__device__ __forceinline__ void g1_lane(cplx (&a)[16], bool hi, cplx u00, cplx u01, cplx u10, cplx u11){
    if constexpr (R < 16) {
        cplx p  = shflx(a[R], LM);
        cplx a0 = hi ? p : a[R];
        cplx a1 = hi ? a[R] : p;
        cplx n0 = cadd(cmul(u00,a0), cmul(u01,a1));
        cplx n1 = cadd(cmul(u10,a0), cmul(u11,a1));
        a[R] = hi ? n1 : n0;
        g1_lane<LM, R+1>(a, hi, u00,u01,u10,u11);
    }
}

template<int W>
__device__ __forceinline__ void apply1q(cplx (&a)[16], int lane, cplx u00, cplx u01, cplx u10, cplx u11){
    if constexpr (W < 4) g1_reg<(1<<W), 0>(a, u00,u01,u10,u11);
    else                 g1_lane<(1<<(W-4)), 0>(a, (lane & (1<<(W-4))) != 0, u00,u01,u10,u11);
}

// ===== CRX(pi/3): diag(I, RX). new0 = cc*a0 - i*ss*a1 ; new1 = -i*ss*a0 + cc*a1 =====

__device__ __forceinline__ void crx_pair(cplx a0, cplx a1, float cc, float ss, cplx &n0, cplx &n1){
    n0 = mk(cc*a0.x + ss*a1.y,  cc*a0.y - ss*a1.x);
    n1 = mk(ss*a0.y + cc*a1.x, -ss*a0.x + cc*a1.y);
}

template<int MC, int MT, int R>
__device__ __forceinline__ void crx_rr(cplx (&a)[16], float cc, float ss){
    if constexpr (R < 16) {
        if constexpr ((R & MC) != 0 && (R & MT) == 0) {
            cplx n0, n1;
            crx_pair(a[R], a[R|MT], cc, ss, n0, n1);
            a[R] = n0; a[R|MT] = n1;
        }
        crx_rr<MC,MT,R+1>(a, cc, ss);
    }
}

template<int MC, int LM, int R>
__device__ __forceinline__ void crx_rl(cplx (&a)[16], bool hi, float cc, float ss){
    if constexpr (R < 16) {
        if constexpr ((R & MC) != 0) {     // compile-time cond: shuffle stays wave-uniform
            cplx p  = shflx(a[R], LM);
            cplx a0 = hi ? p : a[R];
            cplx a1 = hi ? a[R] : p;
            cplx n0, n1;
            crx_pair(a0, a1, cc, ss, n0, n1);
            a[R] = hi ? n1 : n0;
        }
        crx_rl<MC,LM,R+1>(a, hi, cc, ss);
    }
}

template<int MT, int R>
__device__ __forceinline__ void crx_ctrl_pairs(cplx (&a)[16], float cc, float ss){
    if constexpr (R < 16) {
        if constexpr ((R & MT) == 0) {
            cplx n0, n1;
            crx_pair(a[R], a[R|MT], cc, ss, n0, n1);
            a[R] = n0; a[R|MT] = n1;
        }
        crx_ctrl_pairs<MT,R+1>(a, cc, ss);
    }
}

template<int TLM, int R>
__device__ __forceinline__ void crx_ll(cplx (&a)[16], bool ctl, bool hi, float cc, float ss){
    if constexpr (R < 16) {
        cplx p = shflx(a[R], TLM);         // all lanes shuffle; update predicated on ctl
        if (ctl) {
            cplx a0 = hi ? p : a[R];
            cplx a1 = hi ? a[R] : p;
            cplx n0, n1;
            crx_pair(a0, a1, cc, ss, n0, n1);
            a[R] = hi ? n1 : n0;
        }
        crx_ll<TLM,R+1>(a, ctl, hi, cc, ss);
    }
}

template<int C, int T>
__device__ __forceinline__ void apply_crx(cplx (&a)[16], int lane, float cc, float ss){
    if constexpr (C < 4 && T < 4)      crx_rr<(1<<C),(1<<T),0>(a, cc, ss);
    else if constexpr (C < 4)          crx_rl<(1<<C),(1<<(T-4)),0>(a, (lane & (1<<(T-4)))!=0, cc, ss);
    else if constexpr (T < 4)        { if (lane & (1<<(C-4))) crx_ctrl_pairs<(1<<T),0>(a, cc, ss); }
    else                               crx_ll<(1<<(T-4)),0>(a, (lane&(1<<(C-4)))!=0, (lane&(1<<(T-4)))!=0, cc, ss);
}

// ===== CNOT =====

template<int MC, int MT, int R>
__device__ __forceinline__ void cnot_rr(cplx (&a)[16]){
    if constexpr (R < 16) {
        if constexpr ((R & MC) != 0 && (R & MT) == 0) {
            cplx t = a[R]; a[R] = a[R|MT]; a[R|MT] = t;
        }
        cnot_rr<MC,MT,R+1>(a);
    }
}

template<int MC, int LM, int R>
__device__ __forceinline__ void cnot_rl(cplx (&a)[16]){
    if constexpr (R < 16) {
        if constexpr ((R & MC) != 0)
            a[R] = shflx(a[R], LM);        // swap across lanes == take partner's value
        cnot_rl<MC,LM,R+1>(a);
    }
}

template<int MT, int R>
__device__ __forceinline__ void cnot_swap_pairs(cplx (&a)[16]){
    if constexpr (R < 16) {
        if constexpr ((R & MT) == 0) {
            cplx t = a[R]; a[R] = a[R|MT]; a[R|MT] = t;
        }
        cnot_swap_pairs<MT,R+1>(a);
    }
}

template<int TLM, int R>
__device__ __forceinline__ void cnot_ll(cplx (&a)[16], bool ctl){
    if constexpr (R < 16) {
        cplx p = shflx(a[R], TLM);
        if (ctl) a[R] = p;
        cnot_ll<TLM,R+1>(a, ctl);
    }
}

template<int C, int T>
__device__ __forceinline__ void apply_cnot(cplx (&a)[16], int lane){
    if constexpr (C < 4 && T < 4)      cnot_rr<(1<<C),(1<<T),0>(a);
    else if constexpr (C < 4)          cnot_rl<(1<<C),(1<<(T-4)),0>(a);
    else if constexpr (T < 4)        { if (lane & (1<<(C-4))) cnot_swap_pairs<(1<<T),0>(a); }
    else                               cnot_ll<(1<<(T-4)),0>(a, (lane&(1<<(C-4)))!=0);
}

// ===== product-state init: amp = RY(th9)|0> ⊗ ... ⊗ RY(th0)|0> =====
template<int R>
__device__ __forceinline__ void init_state(cplx (&a)[16], float F,
                                           float c0, float s0, float c1, float s1,
                                           float c2, float s2, float c3, float s3){
    if constexpr (R < 16) {
        float g = F;
        g *= (R & 1) ? s0 : c0;
        g *= (R & 2) ? s1 : c1;
        g *= (R & 4) ? s2 : c2;
        g *= (R & 8) ? s3 : c3;
        a[R] = mk(g, 0.f);
        init_state<R+1>(a, F, c0,s0,c1,s1,c2,s2,c3,s3);
    }
}

// ===== probability accumulation =====
template<int R>
__device__ __forceinline__ void accum(const cplx (&a)[16], float &tot,
                                      float &e0, float &e1, float &e2, float &e3){
    if constexpr (R < 16) {
        float p = a[R].x*a[R].x + a[R].y*a[R].y;
        tot += p;
        e0 += (R & 1) ? -p : p;
        e1 += (R & 2) ? -p : p;
        e2 += (R & 4) ? -p : p;
        e3 += (R & 8) ? -p : p;
        accum<R+1>(a, tot, e0, e1, e2, e3);
    }
}

__device__ __forceinline__ float wave_sum(float v){
    v += __shfl_xor(v,  1, 64);
    v += __shfl_xor(v,  2, 64);
    v += __shfl_xor(v,  4, 64);
    v += __shfl_xor(v,  8, 64);
    v += __shfl_xor(v, 16, 64);
    v += __shfl_xor(v, 32, 64);
    return v;
}

__global__ __launch_bounds__(256) void qsim_kernel(const float* __restrict__ inputs,
                                                   const float* __restrict__ weights,
                                                   float* __restrict__ out, int B){
    const int wave = (int)((blockIdx.x * blockDim.x + threadIdx.x) >> 6);
    const int lane = threadIdx.x & 63;
    if (wave >= B) return;

    const float* ang = inputs + (size_t)wave * NQ;

    // ---- AngleEmbedding as a direct product state ----
    float c[NQ], s[NQ];
    #pragma unroll
    for (int w = 0; w < NQ; ++w) __sincosf(0.5f * ang[w], &s[w], &c[w]);

    float F = 1.f;
    F *= (lane &  1) ? s[4] : c[4];
    F *= (lane &  2) ? s[5] : c[5];
    F *= (lane &  4) ? s[6] : c[6];
    F *= (lane &  8) ? s[7] : c[7];
    F *= (lane & 16) ? s[8] : c[8];
    F *= (lane & 32) ? s[9] : c[9];

    cplx amp[16];
    init_state<0>(amp, F, c[0], s[0], c[1], s[1], c[2], s[2], c[3], s[3]);

    // ---- CRX(pi/3) over chain edges ----
    const float cc = 0.86602540378443864676f;  // cos(pi/6)
    const float ss = 0.5f;                     // sin(pi/6)
    apply_crx<0,1>(amp, lane, cc, ss);
    apply_crx<1,2>(amp, lane, cc, ss);
    apply_crx<2,3>(amp, lane, cc, ss);
    apply_crx<3,4>(amp, lane, cc, ss);
    apply_crx<4,5>(amp, lane, cc, ss);
    apply_crx<5,6>(amp, lane, cc, ss);
    apply_crx<6,7>(amp, lane, cc, ss);
    apply_crx<7,8>(amp, lane, cc, ss);
    apply_crx<8,9>(amp, lane, cc, ss);
    apply_crx<9,0>(amp, lane, cc, ss);

    // ---- StronglyEntanglingLayers: Rot on each wire, then CNOT(i, (i+2)%10) ----
    #pragma unroll
    for (int i = 0; i < NQ; ++i) {
        float phi = weights[i*3 + 0], th = weights[i*3 + 1], om = weights[i*3 + 2];
        float ct, st, ca, sa, cb, sb;
        __sincosf(0.5f * th, &st, &ct);
        __sincosf(0.5f * (phi + om), &sa, &ca);
        __sincosf(0.5f * (phi - om), &sb, &cb);
        cplx u00 = mk( ct * ca, -ct * sa);
        cplx u01 = mk(-st * cb, -st * sb);
        cplx u10 = mk( st * cb, -st * sb);
        cplx u11 = mk( ct * ca,  ct * sa);
        switch (i) {  // compile-time wire dispatch (loop fully unrolled; switch folds)
            case 0: apply1q<0>(amp, lane, u00,u01,u10,u11); break;
            case 1: apply1q<1>(amp, lane, u00,u01,u10,u11); break;
            case 2: apply1q<2>(amp, lane, u00,u01,u10,u11); break;
            case 3: apply1q<3>(amp, lane, u00,u01,u10,u11); break;
            case 4: apply1q<4>(amp, lane, u00,u01,u10,u11); break;
            case 5: apply1q<5>(amp, lane, u00,u01,u10,u11); break;
            case 6: apply1q<6>(amp, lane, u00,u01,u10,u11); break;
            case 7: apply1q<7>(amp, lane, u00,u01,u10,u11); break;
            case 8: apply1q<8>(amp, lane, u00,u01,u10,u11); break;
            case 9: apply1q<9>(amp, lane, u00,u01,u10,u11); break;
        }
    }
    apply_cnot<0,2>(amp, lane);
    apply_cnot<1,3>(amp, lane);
    apply_cnot<2,4>(amp, lane);
    apply_cnot<3,5>(amp, lane);
    apply_cnot<4,6>(amp, lane);
    apply_cnot<5,7>(amp, lane);
    apply_cnot<6,8>(amp, lane);
    apply_cnot<7,9>(amp, lane);
    apply_cnot<8,0>(amp, lane);
    apply_cnot<9,1>(amp, lane);

    // ---- expval(PauliZ(w)) ----
    float tot = 0.f, e0 = 0.f, e1 = 0.f, e2 = 0.f, e3 = 0.f;
    accum<0>(amp, tot, e0, e1, e2, e3);

    float r0 = wave_sum(e0);
    float r1 = wave_sum(e1);
    float r2 = wave_sum(e2);
    float r3 = wave_sum(e3);
    float r4 = wave_sum((lane &  1) ? -tot : tot);
    float r5 = wave_sum((lane &  2) ? -tot : tot);
    float r6 = wave_sum((lane &  4) ? -tot : tot);
    float r7 = wave_sum((lane &  8) ? -tot : tot);
    float r8 = wave_sum((lane & 16) ? -tot : tot);
    float r9 = wave_sum((lane & 32) ? -tot : tot);

    if (lane == 0) {
        float* o = out + (size_t)wave * NQ;
        o[0] = r0; o[1] = r1; o[2] = r2; o[3] = r3; o[4] = r4;
        o[5] = r5; o[6] = r6; o[7] = r7; o[8] = r8; o[9] = r9;
    }
}

extern "C" void kernel_launch(void* const* d_in, const int* in_sizes, int n_in,
                              void* d_out, int out_size, void* d_ws, size_t ws_size,
                              hipStream_t stream) {
    const float* inputs  = (const float*)d_in[0];   // (B, 10) float32
    const float* weights = (const float*)d_in[1];   // (1, 10, 3) float32
    float* out = (float*)d_out;                     // (B, 10) float32
    const int B = in_sizes[0] / NQ;
    const int wavesPerBlock = 256 / 64;
    const int blocks = (B + wavesPerBlock - 1) / wavesPerBlock;
    qsim_kernel<<<blocks, 256, 0, stream>>>(inputs, weights, out, B);
}

// Round 3
// 99.096 us; speedup vs baseline: 4.7112x; 1.2711x over previous
//
#include <hip/hip_runtime.h>

#define NQ 10

struct cplx { float x, y; };
__device__ __forceinline__ cplx mk(float x, float y){ cplx c; c.x=x; c.y=y; return c; }
__device__ __forceinline__ cplx shflx(cplx a, int m){
    cplx r; r.x = __shfl_xor(a.x, m, 64); r.y = __shfl_xor(a.y, m, 64); return r;
}

// ===== Rot gate, wire in reg bits: full pair update =====
template<int M, int R>
__device__ __forceinline__ void rot_reg(cplx (&a)[16], cplx u00, cplx u01, cplx u10, cplx u11){
    if constexpr (R < 16) {
        if constexpr ((R & M) == 0) {
            cplx a0 = a[R], a1 = a[R|M];
            a[R]   = mk(u00.x*a0.x - u00.y*a0.y + u01.x*a1.x - u01.y*a1.y,
                        u00.x*a0.y + u00.y*a0.x + u01.x*a1.y + u01.y*a1.x);
            a[R|M] = mk(u10.x*a0.x - u10.y*a0.y + u11.x*a1.x - u11.y*a1.y,
                        u10.x*a0.y + u10.y*a0.x + u11.x*a1.y + u11.y*a1.x);
        }
        rot_reg<M,R+1>(a, u00,u01,u10,u11);
    }
}

// ===== Rot gate, wire in lane bits: coefficient-selected, single output per reg =====
// n = ua*mine + ub*partner   (ua = hi?u11:u00, ub = hi?u10:u01, selected ONCE by caller)
template<int LM, int R>
__device__ __forceinline__ void rot_lane(cplx (&a)[16], cplx ua, cplx ub){
    if constexpr (R < 16) {
        cplx p = shflx(a[R], LM);
        cplx m = a[R];
        a[R] = mk(ua.x*m.x - ua.y*m.y + ub.x*p.x - ub.y*p.y,
                  ua.x*m.y + ua.y*m.x + ub.x*p.y + ub.y*p.x);
        rot_lane<LM,R+1>(a, ua, ub);
    }
}

// ===== CRX(pi/3): symmetric pair op  n = al*mine - i*be*partner =====
// (identical formula for both halves of the pair; al=1,be=0 encodes "control off")

// both wires in reg bits
template<int MC, int MT, int R>
__device__ __forceinline__ void crx_rr(cplx (&a)[16], float cc, float ss){
    if constexpr (R < 16) {
        if constexpr ((R & MC) != 0 && (R & MT) == 0) {
            cplx a0 = a[R], a1 = a[R|MT];
            a[R]    = mk(cc*a0.x + ss*a1.y, cc*a0.y - ss*a1.x);
            a[R|MT] = mk(cc*a1.x + ss*a0.y, cc*a1.y - ss*a0.x);
        }
        crx_rr<MC,MT,R+1>(a, cc, ss);
    }
}

// control in reg bits, target in lane bits (no selects needed at all)
template<int MC, int LM, int R>
__device__ __forceinline__ void crx_rl(cplx (&a)[16], float cc, float ss){
    if constexpr (R < 16) {
        if constexpr ((R & MC) != 0) {
            cplx p = shflx(a[R], LM);
            cplx m = a[R];
            a[R] = mk(cc*m.x + ss*p.y, cc*m.y - ss*p.x);
        }
        crx_rl<MC,LM,R+1>(a, cc, ss);
    }
}

// control in lane bits, target in reg bits: al/be selected once by caller
template<int MT, int R>
__device__ __forceinline__ void crx_lr(cplx (&a)[16], float al, float be){
    if constexpr (R < 16) {
        if constexpr ((R & MT) == 0) {
            cplx a0 = a[R], a1 = a[R|MT];
            a[R]    = mk(al*a0.x + be*a1.y, al*a0.y - be*a1.x);
            a[R|MT] = mk(al*a1.x + be*a0.y, al*a1.y - be*a0.x);
        }
        crx_lr<MT,R+1>(a, al, be);
    }
}

// both wires in lane bits: al/be selected once by caller
template<int TLM, int R>
__device__ __forceinline__ void crx_ll(cplx (&a)[16], float al, float be){
    if constexpr (R < 16) {
        cplx p = shflx(a[R], TLM);
        cplx m = a[R];
        a[R] = mk(al*m.x + be*p.y, al*m.y - be*p.x);
        crx_ll<TLM,R+1>(a, al, be);
    }
}

// ===== product-state init (real amplitudes) =====
template<int R>
__device__ __forceinline__ void init_state(cplx (&a)[16], const float (&v)[16], float F){
    if constexpr (R < 16) {
        a[R] = mk(v[R] * F, 0.f);
        init_state<R+1>(a, v, F);
    }
}

// ===== measurement: 4 signed sums (CNOT cascade folded into parity masks) =====
// SA: sign = b2 ; SB: sign = b3 ; SC: sign = b0^b2 ; SD: sign = b1^b3
template<int R>
__device__ __forceinline__ void accum4(const cplx (&a)[16], float &SA, float &SB, float &SC, float &SD){
    if constexpr (R < 16) {
        float p = a[R].x*a[R].x + a[R].y*a[R].y;
        SA += ((R>>2) & 1)            ? -p : p;
        SB += ((R>>3) & 1)            ? -p : p;
        SC += ((R ^ (R>>2)) & 1)      ? -p : p;
        SD += (((R>>1) ^ (R>>3)) & 1) ? -p : p;
        accum4<R+1>(a, SA, SB, SC, SD);
    }
}

__device__ __forceinline__ float wave_sum(float v){
    v += __shfl_xor(v,  1, 64);
    v += __shfl_xor(v,  2, 64);
    v += __shfl_xor(v,  4, 64);
    v += __shfl_xor(v,  8, 64);
    v += __shfl_xor(v, 16, 64);
    v += __shfl_xor(v, 32, 64);
    return v;
}

__device__ __forceinline__ float fsgn(float v, unsigned s){
    return __uint_as_float(__float_as_uint(v) ^ s);
}
__device__ __forceinline__ unsigned parsgn(int lane, int m){
    return (unsigned)((__builtin_popcount(lane & m) & 1)) << 31;
}

// ===== prep: batch-uniform Rot gate matrices -> d_ws (10 gates x 8 floats) =====
__global__ void prep_gates(const float* __restrict__ weights, float* __restrict__ gates){
    int i = threadIdx.x;
    if (i < NQ) {
        float phi = weights[i*3 + 0], th = weights[i*3 + 1], om = weights[i*3 + 2];
        float ct, st, ca, sa, cb, sb;
        __sincosf(0.5f * th, &st, &ct);
        __sincosf(0.5f * (phi + om), &sa, &ca);
        __sincosf(0.5f * (phi - om), &sb, &cb);
        float* g = gates + i*8;
        g[0] =  ct*ca; g[1] = -ct*sa;   // u00
        g[2] = -st*cb; g[3] = -st*sb;   // u01
        g[4] =  st*cb; g[5] = -st*sb;   // u10
        g[6] =  ct*ca; g[7] =  ct*sa;   // u11
    }
}

__global__ __launch_bounds__(256) void qsim_kernel(const float* __restrict__ inputs,
                                                   const float* __restrict__ gates,
                                                   float* __restrict__ out, int B){
    const int lane = threadIdx.x & 63;
    // force the per-wave sample index into an SGPR so input loads scalarize
    const int wave = __builtin_amdgcn_readfirstlane((int)((blockIdx.x * blockDim.x + threadIdx.x) >> 6));
    if (wave >= B) return;

    const float* ang = inputs + (size_t)wave * NQ;

    // ---- AngleEmbedding as direct product state ----
    float c[NQ], s[NQ];
    #pragma unroll
    for (int w = 0; w < NQ; ++w) __sincosf(0.5f * ang[w], &s[w], &c[w]);

    float F = 1.f;
    F *= (lane &  1) ? s[4] : c[4];
    F *= (lane &  2) ? s[5] : c[5];
    F *= (lane &  4) ? s[6] : c[6];
    F *= (lane &  8) ? s[7] : c[7];
    F *= (lane & 16) ? s[8] : c[8];
    F *= (lane & 32) ? s[9] : c[9];

    // outer product over reg qubits 0..3 (28 mults, no selects)
    float v2[2]  = { c[0], s[0] };
    float v4[4]  = { v2[0]*c[1], v2[1]*c[1], v2[0]*s[1], v2[1]*s[1] };
    float v8[8]  = { v4[0]*c[2], v4[1]*c[2], v4[2]*c[2], v4[3]*c[2],
                     v4[0]*s[2], v4[1]*s[2], v4[2]*s[2], v4[3]*s[2] };
    float v16[16];
    #pragma unroll
    for (int r = 0; r < 8; ++r) { v16[r] = v8[r]*c[3]; v16[r+8] = v8[r]*s[3]; }

    cplx amp[16];
    init_state<0>(amp, v16, F);

    // ---- CRX(pi/3) over chain edges (in EDGES order) ----
    const float cc = 0.86602540378443864676f;  // cos(pi/6)
    const float ss = 0.5f;                     // sin(pi/6)
    crx_rr<1, 2, 0>(amp, cc, ss);                                   // (0,1)
    crx_rr<2, 4, 0>(amp, cc, ss);                                   // (1,2)
    crx_rr<4, 8, 0>(amp, cc, ss);                                   // (2,3)
    crx_rl<8, 1, 0>(amp, cc, ss);                                   // (3,4)
    { bool t = (lane &  1); crx_ll< 2,0>(amp, t?cc:1.f, t?ss:0.f); } // (4,5)
    { bool t = (lane &  2); crx_ll< 4,0>(amp, t?cc:1.f, t?ss:0.f); } // (5,6)
    { bool t = (lane &  4); crx_ll< 8,0>(amp, t?cc:1.f, t?ss:0.f); } // (6,7)
    { bool t = (lane &  8); crx_ll<16,0>(amp, t?cc:1.f, t?ss:0.f); } // (7,8)
    { bool t = (lane & 16); crx_ll<32,0>(amp, t?cc:1.f, t?ss:0.f); } // (8,9)
    { bool t = (lane & 32); crx_lr< 1,0>(amp, t?cc:1.f, t?ss:0.f); } // (9,0)

    // ---- StronglyEntanglingLayers Rot gates (gate matrices from prep kernel) ----
    #define GG(i) mk(gates[(i)*8+0],gates[(i)*8+1]), mk(gates[(i)*8+2],gates[(i)*8+3]), \
                  mk(gates[(i)*8+4],gates[(i)*8+5]), mk(gates[(i)*8+6],gates[(i)*8+7])
    rot_reg<1, 0>(amp, GG(0));
    rot_reg<2, 0>(amp, GG(1));
    rot_reg<4, 0>(amp, GG(2));
    rot_reg<8, 0>(amp, GG(3));
    #undef GG
    #pragma unroll
    for (int w = 4; w < NQ; ++w) {
        const float* g = gates + w*8;
        bool hi = (lane & (1 << (w-4))) != 0;
        cplx ua = mk(hi ? g[6] : g[0], hi ? g[7] : g[1]);  // hi?u11:u00
        cplx ub = mk(hi ? g[4] : g[2], hi ? g[5] : g[3]);  // hi?u10:u01
        switch (w) {
            case 4: rot_lane< 1,0>(amp, ua, ub); break;
            case 5: rot_lane< 2,0>(amp, ua, ub); break;
            case 6: rot_lane< 4,0>(amp, ua, ub); break;
            case 7: rot_lane< 8,0>(amp, ua, ub); break;
            case 8: rot_lane<16,0>(amp, ua, ub); break;
            case 9: rot_lane<32,0>(amp, ua, ub); break;
        }
    }

    // ---- measurement with CNOT cascade folded into parity masks ----
    // <Z_w> = sum_x (-1)^{popcount(x & m_w)} p_x, x = (lane<<4)|r
    // m0={2,4,6,8} m1={3,5,7,9} m2={0,2} m3={1,3} m4={0,2,4} m5={1,3,5}
    // m6={0,2,4,6} m7={1,3,5,7} m8={0,2,4,6,8} m9={1,3,5,7,9}
    float SA = 0.f, SB = 0.f, SC = 0.f, SD = 0.f;
    accum4<0>(amp, SA, SB, SC, SD);

    unsigned p1  = parsgn(lane,  1), p2  = parsgn(lane,  2);
    unsigned p5  = parsgn(lane,  5), p10 = parsgn(lane, 10);
    unsigned p21 = parsgn(lane, 21), p42 = parsgn(lane, 42);

    float r0 = wave_sum(fsgn(SA, p21));
    float r1 = wave_sum(fsgn(SB, p42));
    float r2 = wave_sum(SC);
    float r3 = wave_sum(SD);
    float r4 = wave_sum(fsgn(SC, p1));
    float r5 = wave_sum(fsgn(SD, p2));
    float r6 = wave_sum(fsgn(SC, p5));
    float r7 = wave_sum(fsgn(SD, p10));
    float r8 = wave_sum(fsgn(SC, p21));
    float r9 = wave_sum(fsgn(SD, p42));

    if (lane == 0) {
        float* o = out + (size_t)wave * NQ;
        o[0] = r0; o[1] = r1; o[2] = r2; o[3] = r3; o[4] = r4;
        o[5] = r5; o[6] = r6; o[7] = r7; o[8] = r8; o[9] = r9;
    }
}

extern "C" void kernel_launch(void* const* d_in, const int* in_sizes, int n_in,
                              void* d_out, int out_size, void* d_ws, size_t ws_size,
                              hipStream_t stream) {
    const float* inputs  = (const float*)d_in[0];   // (B, 10) float32
    const float* weights = (const float*)d_in[1];   // (1, 10, 3) float32
    float* out   = (float*)d_out;                   // (B, 10) float32
    float* gates = (float*)d_ws;                    // 80 floats scratch
    const int B = in_sizes[0] / NQ;

    prep_gates<<<1, 64, 0, stream>>>(weights, gates);

    const int wavesPerBlock = 256 / 64;
    const int blocks = (B + wavesPerBlock - 1) / wavesPerBlock;
    qsim_kernel<<<blocks, 256, 0, stream>>>(inputs, gates, out, B);
}